// Round 31
// baseline (91.641 us; speedup 1.0000x reference)
//
#include <hip/hip_runtime.h>

#define NC 32     // num_capsule
#define DC 16     // dim_capsule
#define INC 144   // input capsules
#define IND 8     // input dim
#define NT 512    // threads: (b 0..31) x (cg 0..15); 65536/NT = 128-VGPR cap (empirical law)
#define LG_S 152  // halves per b row of logits

typedef _Float16 h2 __attribute__((ext_vector_type(2)));
typedef _Float16 h4v __attribute__((ext_vector_type(4)));
typedef _Float16 h8 __attribute__((ext_vector_type(8)));
typedef float f4 __attribute__((ext_vector_type(4)));

union H8 { h8 v; h2 p[4]; _Float16 e[8]; };
union WU { uint4 u; h8 v; h2 p[4]; };

#if __has_builtin(__builtin_amdgcn_fdot2)
__device__ __forceinline__ float fdot2(h2 a, h2 b, float c) {
    return __builtin_amdgcn_fdot2(a, b, c, false);
}
#else
__device__ __forceinline__ float fdot2(h2 a, h2 b, float c) {
    return c + (float)a[0] * (float)b[0] + (float)a[1] * (float)b[1];
}
#endif

// Convert+TRANSPOSE W: fp32 [b][c][d][i] -> fp16 h8-slots [(b*9+k)*16+d][cg],
// c = cg + 16k. 73728 h8 slots -> grid 288 x 256.
__global__ void convw_kernel(const float* __restrict__ W, _Float16* __restrict__ Wh) {
    int i = blockIdx.x * 256 + threadIdx.x;          // h8 slot 0..73727
    int cg = i & 15, d = (i >> 4) & 15, bk = i >> 8; // bk = b*9+k, 0..287
    int k = bk % 9, b = bk / 9;
    const float* s = W + (((size_t)b * INC + cg + 16 * k) * DC + d) * IND;
    f4 v0 = *reinterpret_cast<const f4*>(s);
    f4 v1 = *reinterpret_cast<const f4*>(s + 4);
    H8 o;
    o.e[0] = (_Float16)v0[0]; o.e[1] = (_Float16)v0[1];
    o.e[2] = (_Float16)v0[2]; o.e[3] = (_Float16)v0[3];
    o.e[4] = (_Float16)v1[0]; o.e[5] = (_Float16)v1[1];
    o.e[6] = (_Float16)v1[2]; o.e[7] = (_Float16)v1[3];
    *reinterpret_cast<h8*>(Wh + (size_t)i * 8) = o.v;
}

#define R9(M)  M(0) M(1) M(2) M(3) M(4) M(5) M(6) M(7) M(8)
#define R16(M) M(0) M(1) M(2) M(3) M(4) M(5) M(6) M(7) M(8) M(9) M(10) M(11) M(12) M(13) M(14) M(15)

template <typename WT>
__global__ __launch_bounds__(NT)
void caps_kernel(const float* __restrict__ xg, const WT* __restrict__ Wg,
                 float* __restrict__ out) {
    // LDS: only truly-shared state (~12.5 KB)
    __shared__ __align__(16) _Float16 x_h[INC * IND];   // 2304 B
    __shared__ __align__(16) _Float16 lg[NC * LG_S];    // 9728 B
    __shared__ __align__(16) _Float16 o_buf[NC * DC];   // 512 B

    const int t = threadIdx.x;
    const int b = t >> 4;    // capsule
    const int cg = t & 15;   // c-group: owns c = cg + 16k, all 16 d
    const int a = blockIdx.x;

    // ---- load x[a]: 1152 floats = 288 f4 -> fp16 LDS ----
    if (t < 288) {
        f4 v = reinterpret_cast<const f4*>(xg + (size_t)a * (INC * IND))[t];
        h4v hv;
        hv[0] = (_Float16)v[0]; hv[1] = (_Float16)v[1];
        hv[2] = (_Float16)v[2]; hv[3] = (_Float16)v[3];
        *reinterpret_cast<h4v*>(x_h + t * 4) = hv;
    }
    __syncthreads();

    // hat rows in 18 NAMED uint4 registers (owner-only; r30 proved this
    // materializes at VGPR=128 -- but spilled ~7 regs because s0..s15 were
    // live through H. Fix: s-sum moved POST-H so H-peak is just hat+temps).
#define DECLH(K) uint4 hL##K, hH##K;
    R9(DECLH)
#define DECLS(D) float s##D;
    R16(DECLS)
#define ZEROS(D) s##D = 0.f;

    // one d of one c: 16B W load + 4-chain fdot2; pack fp16 (NO s-accum)
#define HD1(T, E, DG) { \
    WU w; w.u = *reinterpret_cast<const uint4*>(wrb + (DG) * 256); \
    float ac = fdot2(w.p[0], xv.p[0], 0.f); \
    ac = fdot2(w.p[1], xv.p[1], ac); \
    ac = fdot2(w.p[2], xv.p[2], ac); \
    ac = fdot2(w.p[3], xv.p[3], ac); \
    T.e[E] = (_Float16)ac; }

#define HD1F(T, E, DG) { \
    const float* wf = wfr + (DG) * IND; \
    f4 w0 = *reinterpret_cast<const f4*>(wf); \
    f4 w1 = *reinterpret_cast<const f4*>(wf + 4); \
    float ac = (float)xv.e[0] * w0[0]; \
    ac = fmaf((float)xv.e[1], w0[1], ac); \
    ac = fmaf((float)xv.e[2], w0[2], ac); \
    ac = fmaf((float)xv.e[3], w0[3], ac); \
    ac = fmaf((float)xv.e[4], w1[0], ac); \
    ac = fmaf((float)xv.e[5], w1[1], ac); \
    ac = fmaf((float)xv.e[6], w1[2], ac); \
    ac = fmaf((float)xv.e[7], w1[3], ac); \
    T.e[E] = (_Float16)ac; }

#define HSTEP(K) { \
    const int c = cg + 16 * (K); \
    H8 xv; xv.v = *reinterpret_cast<const h8*>(x_h + c * IND); \
    H8 tL, tH; \
    if constexpr (sizeof(WT) == 2) { \
        const char* wrb = reinterpret_cast<const char*>(Wg) + \
                          (size_t)(b * 9 + (K)) * 4096 + cg * 16; \
        HD1(tL,0,0) HD1(tL,1,1) HD1(tL,2,2) HD1(tL,3,3) \
        HD1(tL,4,4) HD1(tL,5,5) HD1(tL,6,6) HD1(tL,7,7) \
        HD1(tH,0,8) HD1(tH,1,9) HD1(tH,2,10) HD1(tH,3,11) \
        HD1(tH,4,12) HD1(tH,5,13) HD1(tH,6,14) HD1(tH,7,15) \
    } else { \
        const float* wfr = reinterpret_cast<const float*>(Wg) + \
                           (size_t)(b * INC + c) * (DC * IND); \
        HD1F(tL,0,0) HD1F(tL,1,1) HD1F(tL,2,2) HD1F(tL,3,3) \
        HD1F(tL,4,4) HD1F(tL,5,5) HD1F(tL,6,6) HD1F(tL,7,7) \
        HD1F(tH,0,8) HD1F(tH,1,9) HD1F(tH,2,10) HD1F(tH,3,11) \
        HD1F(tH,4,12) HD1F(tH,5,13) HD1F(tH,6,14) HD1F(tH,7,15) \
    } \
    WU uL, uH; uL.v = tL.v; uH.v = tH.v; \
    hL##K = uL.u; hH##K = uH.u; }

    R9(HSTEP)

    // post-H s0-sum from hat registers (adds only; same fp16-rounded source
    // of truth the S-passes use; r15 validated numerics, absmax 1.22e-4)
#define S0ADD(K) { \
    WU hl, hh; hl.u = hL##K; hh.u = hH##K; \
    H8 e1, e2; e1.v = hl.v; e2.v = hh.v; \
    s0  += (float)e1.e[0];  s1  += (float)e1.e[1]; \
    s2  += (float)e1.e[2];  s3  += (float)e1.e[3]; \
    s4  += (float)e1.e[4];  s5  += (float)e1.e[5]; \
    s6  += (float)e1.e[6];  s7  += (float)e1.e[7]; \
    s8  += (float)e2.e[0];  s9  += (float)e2.e[1]; \
    s10 += (float)e2.e[2];  s11 += (float)e2.e[3]; \
    s12 += (float)e2.e[4];  s13 += (float)e2.e[5]; \
    s14 += (float)e2.e[6];  s15 += (float)e2.e[7]; }

    R16(ZEROS)
    R9(S0ADD)

    // ---- recursive-halving transpose-reduce (15 shuffles), r25-proven ----
    const bool c8 = (cg & 8) != 0, c4 = (cg & 4) != 0;
    const bool c2 = (cg & 2) != 0, c1 = (cg & 1) != 0;
#define HV(A, B, M, CB) { float snd_ = (CB) ? s##A : s##B; \
                          float kp_ = (CB) ? s##B : s##A; \
                          s##A = kp_ + __shfl_xor(snd_, M, 16); }
#define HALVE16 \
    HV(0,8,8,c8) HV(1,9,8,c8) HV(2,10,8,c8) HV(3,11,8,c8) \
    HV(4,12,8,c8) HV(5,13,8,c8) HV(6,14,8,c8) HV(7,15,8,c8) \
    HV(0,4,4,c4) HV(1,5,4,c4) HV(2,6,4,c4) HV(3,7,4,c4) \
    HV(0,2,2,c2) HV(1,3,2,c2) \
    HV(0,1,1,c1)

#define SQUASH1(RS, OVAL) \
    float r_ = s0 * (RS); \
    float n2_ = r_ * r_; \
    n2_ += __shfl_xor(n2_, 1, 16); n2_ += __shfl_xor(n2_, 2, 16); \
    n2_ += __shfl_xor(n2_, 4, 16); n2_ += __shfl_xor(n2_, 8, 16); \
    float OVAL = r_ * (n2_ / ((1.0f + n2_) * sqrtf(n2_ + 1e-7f)));

#define OBCAST(OVAL) \
    o_buf[b * DC + cg] = (_Float16)(OVAL); \
    __threadfence_block(); \
    oLv = *reinterpret_cast<const h8*>(o_buf + b * DC); \
    oHv = *reinterpret_cast<const h8*>(o_buf + b * DC + 8);

    h8 oLv, oHv;
    HALVE16
    {
        SQUASH1(1.0f / 32.0f, oval)  // softmax(0) uniform coefficients
        OBCAST(oval)
    }

#define DECLG(K) float lgr##K = 0.f;
    R9(DECLG)

    // B-pass: logit[b][c] += o . hat[b][c][:] -- hat from REGISTERS
#define BSTEP(K) { \
    WU hl, hh; hl.u = hL##K; hh.u = hH##K; \
    H8 ol, oh; ol.v = oLv; oh.v = oHv; \
    float dt  = fdot2(hl.p[0], ol.p[0], 0.f); \
    float dt2 = fdot2(hl.p[1], ol.p[1], 0.f); \
    dt  = fdot2(hl.p[2], ol.p[2], dt); \
    dt2 = fdot2(hl.p[3], ol.p[3], dt2); \
    dt  = fdot2(hh.p[0], oh.p[0], dt); \
    dt2 = fdot2(hh.p[1], oh.p[1], dt2); \
    dt  = fdot2(hh.p[2], oh.p[2], dt); \
    dt2 = fdot2(hh.p[3], oh.p[3], dt2); \
    lgr##K += dt + dt2; \
    lg[b * LG_S + cg + 16 * (K)] = (_Float16)lgr##K; }

    // S-pass: s_d += cc[b][c] * hat[c][d] -- hat from REGISTERS
#define SSTEP(K) { \
    float cf = (float)lg[b * LG_S + cg + 16 * (K)]; \
    WU hl, hh; hl.u = hL##K; hh.u = hH##K; \
    H8 hle, hhe; hle.v = hl.v; hhe.v = hh.v; \
    s0  = fmaf(cf, (float)hle.e[0], s0);  s1  = fmaf(cf, (float)hle.e[1], s1); \
    s2  = fmaf(cf, (float)hle.e[2], s2);  s3  = fmaf(cf, (float)hle.e[3], s3); \
    s4  = fmaf(cf, (float)hle.e[4], s4);  s5  = fmaf(cf, (float)hle.e[5], s5); \
    s6  = fmaf(cf, (float)hle.e[6], s6);  s7  = fmaf(cf, (float)hle.e[7], s7); \
    s8  = fmaf(cf, (float)hhe.e[0], s8);  s9  = fmaf(cf, (float)hhe.e[1], s9); \
    s10 = fmaf(cf, (float)hhe.e[2], s10); s11 = fmaf(cf, (float)hhe.e[3], s11); \
    s12 = fmaf(cf, (float)hhe.e[4], s12); s13 = fmaf(cf, (float)hhe.e[5], s13); \
    s14 = fmaf(cf, (float)hhe.e[6], s14); s15 = fmaf(cf, (float)hhe.e[7], s15); }

    for (int it = 0; it < 2; ++it) {
        R9(BSTEP)
        __syncthreads();

        // softmax over 32 capsules: 2 threads per c, 16 bb's each, named regs
        if (t < 2 * INC) {
            const int c = t >> 1;
            const int rb = (t & 1) * 16;
#define SMR(I) float v##I = (float)lg[(rb + I) * LG_S + c];
            R16(SMR)
            float m = fmaxf(v0, v1);
#define SMM(I) m = fmaxf(m, v##I);
            SMM(2) SMM(3) SMM(4) SMM(5) SMM(6) SMM(7) SMM(8) SMM(9)
            SMM(10) SMM(11) SMM(12) SMM(13) SMM(14) SMM(15)
            m = fmaxf(m, __shfl_xor(m, 1));
            float S = 0.f;
#define SME(I) v##I = __expf(v##I - m); S += v##I;
            R16(SME)
            S += __shfl_xor(S, 1);
            float inv = 1.0f / S;
#define SMW(I) lg[(rb + I) * LG_S + c] = (_Float16)(v##I * inv);
            R16(SMW)
        }
        __syncthreads();

        R16(ZEROS)
        R9(SSTEP)
        HALVE16

        if (it == 0) {
            SQUASH1(1.0f, oval)
            OBCAST(oval)
            __syncthreads();  // S-reads of lg done before next B-pass writes
        } else {
            SQUASH1(1.0f, oval)
            out[(size_t)a * (NC * DC) + t] = oval;  // lane cg = dim cg: coalesced
        }
    }
}

extern "C" void kernel_launch(void* const* d_in, const int* in_sizes, int n_in,
                              void* d_out, int out_size, void* d_ws, size_t ws_size,
                              hipStream_t stream) {
    const float* x = (const float*)d_in[0];
    const float* W = (const float*)d_in[1];
    float* out = (float*)d_out;

    const size_t WH_BYTES = (size_t)NC * INC * DC * IND * 2;  // 1179648

    if (ws_size >= WH_BYTES) {
        _Float16* Wh = (_Float16*)d_ws;
        hipLaunchKernelGGL(convw_kernel, dim3(288), dim3(256), 0, stream, W, Wh);
        hipLaunchKernelGGL(caps_kernel<_Float16>, dim3(512), dim3(NT), 0,
                           stream, x, Wh, out);
    } else {
        hipLaunchKernelGGL(caps_kernel<float>, dim3(512), dim3(NT), 0,
                           stream, x, W, out);
    }
}

// Round 32
// 44.668 us; speedup vs baseline: 2.0516x; 2.0516x over previous
//
#include <hip/hip_runtime.h>

#define NC 32     // num_capsule
#define DC 16     // dim_capsule
#define INC 144   // input capsules
#define IND 8     // input dim
#define NT 512    // threads: (b 0..31) x (cg 0..15)
#define LG_S 152  // halves per b row of logits

// LDS (halves): hatL[32][144][8] | pad | hatH[32][144][8] | lg[32][152] (x overlaps lg) | o_buf[32][16]
#define HATL_OFF 0
#define HATH_OFF (NC * INC * IND + 8)          // 36872; 16B-aligned
#define LG_OFF (HATH_OFF + NC * INC * IND)     // 73736; 16B-aligned
#define OB_OFF (LG_OFF + NC * LG_S)            // 78600; 16B-aligned
#define SMEM_HALVES (OB_OFF + NC * DC)         // 79112
#define SMEM_BYTES (SMEM_HALVES * 2)           // 158224 <= 163840

typedef _Float16 h2 __attribute__((ext_vector_type(2)));
typedef _Float16 h4v __attribute__((ext_vector_type(4)));
typedef _Float16 h8 __attribute__((ext_vector_type(8)));
typedef float f4 __attribute__((ext_vector_type(4)));

union H8 { h8 v; h2 p[4]; _Float16 e[8]; };
union WU { uint4 u; h8 v; h2 p[4]; };

#if __has_builtin(__builtin_amdgcn_fdot2)
__device__ __forceinline__ float fdot2(h2 a, h2 b, float c) {
    return __builtin_amdgcn_fdot2(a, b, c, false);
}
#else
__device__ __forceinline__ float fdot2(h2 a, h2 b, float c) {
    return c + (float)a[0] * (float)b[0] + (float)a[1] * (float)b[1];
}
#endif

// Convert+TRANSPOSE W: fp32 [b][c][d][i] -> fp16 h8-slots [(b*9+k)*16+d][cg],
// c = cg + 16k. 73728 h8 slots -> grid 288 x 256.
__global__ void convw_kernel(const float* __restrict__ W, _Float16* __restrict__ Wh) {
    int i = blockIdx.x * 256 + threadIdx.x;          // h8 slot 0..73727
    int cg = i & 15, d = (i >> 4) & 15, bk = i >> 8; // bk = b*9+k, 0..287
    int k = bk % 9, b = bk / 9;
    const float* s = W + (((size_t)b * INC + cg + 16 * k) * DC + d) * IND;
    f4 v0 = *reinterpret_cast<const f4*>(s);
    f4 v1 = *reinterpret_cast<const f4*>(s + 4);
    H8 o;
    o.e[0] = (_Float16)v0[0]; o.e[1] = (_Float16)v0[1];
    o.e[2] = (_Float16)v0[2]; o.e[3] = (_Float16)v0[3];
    o.e[4] = (_Float16)v1[0]; o.e[5] = (_Float16)v1[1];
    o.e[6] = (_Float16)v1[2]; o.e[7] = (_Float16)v1[3];
    *reinterpret_cast<h8*>(Wh + (size_t)i * 8) = o.v;
}

#define R9(M)  M(0) M(1) M(2) M(3) M(4) M(5) M(6) M(7) M(8)
#define R16(M) M(0) M(1) M(2) M(3) M(4) M(5) M(6) M(7) M(8) M(9) M(10) M(11) M(12) M(13) M(14) M(15)

template <typename WT>
__global__ __launch_bounds__(NT)
__attribute__((amdgpu_waves_per_eu(2, 4)))
void caps_kernel(const float* __restrict__ xg, const WT* __restrict__ Wg,
                 float* __restrict__ out) {
    extern __shared__ __align__(16) _Float16 sm[];
    _Float16* lg = sm + LG_OFF;
    _Float16* o_buf = sm + OB_OFF;
    _Float16* x_h = lg;  // overlap: x only live during phase H (barrier before lg use)

    const int t = threadIdx.x;
    const int b = t >> 4;    // capsule
    const int cg = t & 15;   // c-group: owns c = cg + 16k, all 16 d
    const int a = blockIdx.x;

    // ---- load x[a]: 1152 floats = 288 f4 -> fp16 LDS ----
    if (t < 288) {
        f4 v = reinterpret_cast<const f4*>(xg + (size_t)a * (INC * IND))[t];
        h4v hv;
        hv[0] = (_Float16)v[0]; hv[1] = (_Float16)v[1];
        hv[2] = (_Float16)v[2]; hv[3] = (_Float16)v[3];
        *reinterpret_cast<h4v*>(x_h + t * 4) = hv;
    }
    __syncthreads();

#define DECLS(D) float s##D;
    R16(DECLS)
#define ZEROS(D) s##D = 0.f;
    R16(ZEROS)

    // ---- Phase H, software-pipelined (r24): 8-deep uint4 double-buffer ----
#define WADDR(K, DG) reinterpret_cast<const uint4*>( \
    reinterpret_cast<const char*>(Wg) + (size_t)(b * 9 + (K)) * 4096 + (DG) * 256 + cg * 16)

#define PREA(K) { wA0 = *WADDR(K,0); wA1 = *WADDR(K,1); wA2 = *WADDR(K,2); \
                  wA3 = *WADDR(K,3); wA4 = *WADDR(K,4); wA5 = *WADDR(K,5); \
                  wA6 = *WADDR(K,6); wA7 = *WADDR(K,7); }
#define PREB(K) { wB0 = *WADDR(K,8); wB1 = *WADDR(K,9); wB2 = *WADDR(K,10); \
                  wB3 = *WADDR(K,11); wB4 = *WADDR(K,12); wB5 = *WADDR(K,13); \
                  wB6 = *WADDR(K,14); wB7 = *WADDR(K,15); }

#define HD1R(WREG, T, E, SD) { \
    WU w; w.u = WREG; \
    float ac = fdot2(w.p[0], xv.p[0], 0.f); \
    ac = fdot2(w.p[1], xv.p[1], ac); \
    ac = fdot2(w.p[2], xv.p[2], ac); \
    ac = fdot2(w.p[3], xv.p[3], ac); \
    T.e[E] = (_Float16)ac; s##SD += ac; }

#define CMPA(T) HD1R(wA0,T,0,0) HD1R(wA1,T,1,1) HD1R(wA2,T,2,2) HD1R(wA3,T,3,3) \
                HD1R(wA4,T,4,4) HD1R(wA5,T,5,5) HD1R(wA6,T,6,6) HD1R(wA7,T,7,7)
#define CMPB(T) HD1R(wB0,T,0,8) HD1R(wB1,T,1,9) HD1R(wB2,T,2,10) HD1R(wB3,T,3,11) \
                HD1R(wB4,T,4,12) HD1R(wB5,T,5,13) HD1R(wB6,T,6,14) HD1R(wB7,T,7,15)

#define HPIPE(K, KN) { \
    const int c = cg + 16 * (K); \
    H8 xv; xv.v = *reinterpret_cast<const h8*>(x_h + c * IND); \
    H8 tL, tH; \
    CMPA(tL) \
    PREA(KN) \
    CMPB(tH) \
    PREB(KN) \
    *reinterpret_cast<h8*>(sm + HATL_OFF + (size_t)(b * INC + c) * 8) = tL.v; \
    *reinterpret_cast<h8*>(sm + HATH_OFF + (size_t)(b * INC + c) * 8) = tH.v; }

#define HD1F(T, E, DG) { \
    const float* wf = wfr + (DG) * IND; \
    f4 w0 = *reinterpret_cast<const f4*>(wf); \
    f4 w1 = *reinterpret_cast<const f4*>(wf + 4); \
    float ac = (float)xv.e[0] * w0[0]; \
    ac = fmaf((float)xv.e[1], w0[1], ac); \
    ac = fmaf((float)xv.e[2], w0[2], ac); \
    ac = fmaf((float)xv.e[3], w0[3], ac); \
    ac = fmaf((float)xv.e[4], w1[0], ac); \
    ac = fmaf((float)xv.e[5], w1[1], ac); \
    ac = fmaf((float)xv.e[6], w1[2], ac); \
    ac = fmaf((float)xv.e[7], w1[3], ac); \
    T.e[E] = (_Float16)ac; s##DG += ac; }

#define HSTEPF(K) { \
    const int c = cg + 16 * (K); \
    H8 xv; xv.v = *reinterpret_cast<const h8*>(x_h + c * IND); \
    const float* wfr = reinterpret_cast<const float*>(Wg) + \
                       (size_t)(b * INC + c) * (DC * IND); \
    H8 tL, tH; \
    HD1F(tL,0,0) HD1F(tL,1,1) HD1F(tL,2,2) HD1F(tL,3,3) \
    HD1F(tL,4,4) HD1F(tL,5,5) HD1F(tL,6,6) HD1F(tL,7,7) \
    HD1F(tH,0,8) HD1F(tH,1,9) HD1F(tH,2,10) HD1F(tH,3,11) \
    HD1F(tH,4,12) HD1F(tH,5,13) HD1F(tH,6,14) HD1F(tH,7,15) \
    *reinterpret_cast<h8*>(sm + HATL_OFF + (size_t)(b * INC + c) * 8) = tL.v; \
    *reinterpret_cast<h8*>(sm + HATH_OFF + (size_t)(b * INC + c) * 8) = tH.v; }

    if constexpr (sizeof(WT) == 2) {
        uint4 wA0, wA1, wA2, wA3, wA4, wA5, wA6, wA7;
        uint4 wB0, wB1, wB2, wB3, wB4, wB5, wB6, wB7;
        PREA(0) PREB(0)
        HPIPE(0, 1) HPIPE(1, 2) HPIPE(2, 3) HPIPE(3, 4) HPIPE(4, 5)
        HPIPE(5, 6) HPIPE(6, 7) HPIPE(7, 8) HPIPE(8, 8)  // last: benign reload
    } else {
        R9(HSTEPF)
    }
    __syncthreads();  // x_h reads done everywhere before B-pass writes lg (overlap)

    // ---- Recursive-halving transpose-reduce: lane cg ends with the FULL
    // sum of s_cg. 15 shuffles vs 64 for allreduce. ----
    const bool c8 = (cg & 8) != 0, c4 = (cg & 4) != 0;
    const bool c2 = (cg & 2) != 0, c1 = (cg & 1) != 0;
#define HV(A, B, M, CB) { float snd_ = (CB) ? s##A : s##B; \
                          float kp_ = (CB) ? s##B : s##A; \
                          s##A = kp_ + __shfl_xor(snd_, M, 16); }
#define HALVE16 \
    HV(0,8,8,c8) HV(1,9,8,c8) HV(2,10,8,c8) HV(3,11,8,c8) \
    HV(4,12,8,c8) HV(5,13,8,c8) HV(6,14,8,c8) HV(7,15,8,c8) \
    HV(0,4,4,c4) HV(1,5,4,c4) HV(2,6,4,c4) HV(3,7,4,c4) \
    HV(0,2,2,c2) HV(1,3,2,c2) \
    HV(0,1,1,c1)

    // squash from distributed s (lane cg holds s_cg): 4-shuffle n2 butterfly
#define SQUASH1(RS, OVAL) \
    float r_ = s0 * (RS); \
    float n2_ = r_ * r_; \
    n2_ += __shfl_xor(n2_, 1, 16); n2_ += __shfl_xor(n2_, 2, 16); \
    n2_ += __shfl_xor(n2_, 4, 16); n2_ += __shfl_xor(n2_, 8, 16); \
    float OVAL = r_ * (n2_ / ((1.0f + n2_) * sqrtf(n2_ + 1e-7f)));

    // rebuild full o-vector per lane: same-wave LDS broadcast (b-group local)
#define OBCAST(OVAL) \
    o_buf[b * DC + cg] = (_Float16)(OVAL); \
    __threadfence_block(); \
    oLv = *reinterpret_cast<const h8*>(o_buf + b * DC); \
    oHv = *reinterpret_cast<const h8*>(o_buf + b * DC + 8);

    h8 oLv, oHv;
    HALVE16
    {
        SQUASH1(1.0f / 32.0f, oval)  // softmax(0) uniform coefficients
        OBCAST(oval)
    }

#define DECLG(K) float lgr##K = 0.f;
    R9(DECLG)

    // B-pass: logit[b][c] += o . hat[b][c][:] -- own LDS rows, chain-split
#define BSTEP(K) { \
    const int c = cg + 16 * (K); \
    H8 hl, hh; \
    hl.v = *reinterpret_cast<const h8*>(sm + HATL_OFF + (size_t)(b * INC + c) * 8); \
    hh.v = *reinterpret_cast<const h8*>(sm + HATH_OFF + (size_t)(b * INC + c) * 8); \
    H8 ol, oh; ol.v = oLv; oh.v = oHv; \
    float dt  = fdot2(hl.p[0], ol.p[0], 0.f); \
    float dt2 = fdot2(hl.p[1], ol.p[1], 0.f); \
    dt  = fdot2(hl.p[2], ol.p[2], dt); \
    dt2 = fdot2(hl.p[3], ol.p[3], dt2); \
    dt  = fdot2(hh.p[0], oh.p[0], dt); \
    dt2 = fdot2(hh.p[1], oh.p[1], dt2); \
    dt  = fdot2(hh.p[2], oh.p[2], dt); \
    dt2 = fdot2(hh.p[3], oh.p[3], dt2); \
    lgr##K += dt + dt2; \
    lg[b * LG_S + c] = (_Float16)lgr##K; }

    // S-pass: s_d += cc[b][c] * hat[c][d] over own 9 c's (16 indep chains)
#define SSTEP(K) { \
    const int c = cg + 16 * (K); \
    float cf = (float)lg[b * LG_S + c]; \
    H8 hl, hh; \
    hl.v = *reinterpret_cast<const h8*>(sm + HATL_OFF + (size_t)(b * INC + c) * 8); \
    hh.v = *reinterpret_cast<const h8*>(sm + HATH_OFF + (size_t)(b * INC + c) * 8); \
    s0  = fmaf(cf, (float)hl.e[0], s0);  s1  = fmaf(cf, (float)hl.e[1], s1); \
    s2  = fmaf(cf, (float)hl.e[2], s2);  s3  = fmaf(cf, (float)hl.e[3], s3); \
    s4  = fmaf(cf, (float)hl.e[4], s4);  s5  = fmaf(cf, (float)hl.e[5], s5); \
    s6  = fmaf(cf, (float)hl.e[6], s6);  s7  = fmaf(cf, (float)hl.e[7], s7); \
    s8  = fmaf(cf, (float)hh.e[0], s8);  s9  = fmaf(cf, (float)hh.e[1], s9); \
    s10 = fmaf(cf, (float)hh.e[2], s10); s11 = fmaf(cf, (float)hh.e[3], s11); \
    s12 = fmaf(cf, (float)hh.e[4], s12); s13 = fmaf(cf, (float)hh.e[5], s13); \
    s14 = fmaf(cf, (float)hh.e[6], s14); s15 = fmaf(cf, (float)hh.e[7], s15); }

    for (int it = 0; it < 2; ++it) {
        R9(BSTEP)
        __syncthreads();

        // softmax over 32 capsules: 2 threads per c, 16 bb's each, named regs
        if (t < 2 * INC) {
            const int c = t >> 1;
            const int rb = (t & 1) * 16;
#define SMR(I) float v##I = (float)lg[(rb + I) * LG_S + c];
            R16(SMR)
            float m = fmaxf(v0, v1);
#define SMM(I) m = fmaxf(m, v##I);
            SMM(2) SMM(3) SMM(4) SMM(5) SMM(6) SMM(7) SMM(8) SMM(9)
            SMM(10) SMM(11) SMM(12) SMM(13) SMM(14) SMM(15)
            m = fmaxf(m, __shfl_xor(m, 1));
            float S = 0.f;
#define SME(I) v##I = __expf(v##I - m); S += v##I;
            R16(SME)
            S += __shfl_xor(S, 1);
            float inv = 1.0f / S;
#define SMW(I) lg[(rb + I) * LG_S + c] = (_Float16)(v##I * inv);
            R16(SMW)
        }
        __syncthreads();

        R16(ZEROS)
        R9(SSTEP)
        HALVE16

        if (it == 0) {
            SQUASH1(1.0f, oval)
            OBCAST(oval)
            __syncthreads();  // S-reads of lg done before next B-pass writes
        } else {
            SQUASH1(1.0f, oval)
            out[(size_t)a * (NC * DC) + t] = oval;  // lane cg = dim cg: coalesced
        }
    }
}

extern "C" void kernel_launch(void* const* d_in, const int* in_sizes, int n_in,
                              void* d_out, int out_size, void* d_ws, size_t ws_size,
                              hipStream_t stream) {
    const float* x = (const float*)d_in[0];
    const float* W = (const float*)d_in[1];
    float* out = (float*)d_out;

    const size_t WH_BYTES = (size_t)NC * INC * DC * IND * 2;  // 1179648

    if (ws_size >= WH_BYTES) {
        _Float16* Wh = (_Float16*)d_ws;
        hipLaunchKernelGGL(convw_kernel, dim3(288), dim3(256), 0, stream, W, Wh);
        hipFuncSetAttribute(reinterpret_cast<const void*>(&caps_kernel<_Float16>),
                            hipFuncAttributeMaxDynamicSharedMemorySize, SMEM_BYTES);
        hipLaunchKernelGGL(caps_kernel<_Float16>, dim3(512), dim3(NT), SMEM_BYTES,
                           stream, x, Wh, out);
    } else {
        hipFuncSetAttribute(reinterpret_cast<const void*>(&caps_kernel<float>),
                            hipFuncAttributeMaxDynamicSharedMemorySize, SMEM_BYTES);
        hipLaunchKernelGGL(caps_kernel<float>, dim3(512), dim3(NT), SMEM_BYTES,
                           stream, x, W, out);
    }
}